// Round 1
// baseline (1643.283 us; speedup 1.0000x reference)
//
#include <hip/hip_runtime.h>
#include <hip/hip_bf16.h>

typedef short short8 __attribute__((ext_vector_type(8)));
typedef float f32x16 __attribute__((ext_vector_type(16)));
typedef float f32x4 __attribute__((ext_vector_type(4)));

// ---------- bf16 helpers (RNE) ----------
__device__ __forceinline__ unsigned short f2bf(float f) {
  union { float f; unsigned int u; } v; v.f = f;
  unsigned int u = v.u;
  unsigned int r = u + 0x7FFFu + ((u >> 16) & 1u);
  return (unsigned short)(r >> 16);
}
__device__ __forceinline__ float bf2f(unsigned short s) {
  union { unsigned int u; float f; } v; v.u = ((unsigned int)s) << 16;
  return v.f;
}

// ---------- erf / GELU (A&S 7.1.26, |err| <= 1.5e-7) ----------
__device__ __forceinline__ float erfc_core(float u) {  // ~erfc(u), u>=0
  float e = __expf(-u * u);
  float d = fmaf(0.3275911f, u, 1.0f);
  float r = __builtin_amdgcn_rcpf(d);
  float p = fmaf(1.061405429f, r, -1.453152027f);
  p = fmaf(p, r, 1.421413741f);
  p = fmaf(p, r, -0.284496736f);
  p = fmaf(p, r, 0.254829592f);
  p = p * r;
  return p * e;
}
__device__ __forceinline__ float gelu_erf(float t) {
  float u = fabsf(t) * 0.7071067811865475f;
  float w = erfc_core(u);
  float h = 0.5f * fabsf(t);
  // gelu = 0.5t + h*(1-w)
  return fmaf(-h, w, fmaf(0.5f, t, h));
}

// ---------- precompute per-(graph,channel) GELU Taylor coeffs ----------
// t0 = b1[c] + sum_k h[g][k]*W1[1+k][c] + 0.5*W1[0][c]
// p0 = GELU(t0), p1 = GELU'(t0), p2 = 0.5*GELU''(t0)
__global__ void k_graph(const float* __restrict__ h, const float* __restrict__ W1,
                        const float* __restrict__ b1,
                        float* __restrict__ p0, float* __restrict__ p1,
                        float* __restrict__ p2) {
  __shared__ float hs[128];
  int g = blockIdx.x, c = threadIdx.x;
  if (c < 128) hs[c] = h[g * 128 + c];
  __syncthreads();
  float acc = b1[c];
#pragma unroll 8
  for (int k = 0; k < 128; k++)
    acc = fmaf(hs[k], W1[(1 + k) * 256 + c], acc);
  float t0 = fmaf(0.5f, W1[c], acc);
  float u = fabsf(t0) * 0.7071067811865475f;
  float wq = erfc_core(u);
  float Phi = (t0 >= 0.f) ? fmaf(-0.5f, wq, 1.0f) : 0.5f * wq;
  float phi = 0.3989422804f * __expf(-0.5f * t0 * t0);
  int o = g * 256 + c;
  p0[o] = t0 * Phi;
  p1[o] = fmaf(t0, phi, Phi);
  p2[o] = phi * fmaf(-0.5f * t0, t0, 1.0f);
}

// ---------- pack W2/W3 into per-lane MFMA A-fragment order, bf16 hi+lo ----------
// frag index layout: ((chtile*16 + kstep)*64 + lane)*8 + j
// k  = kstep*16 + (lane>>5)*8 + j ; ch = chtile*32 + (lane&31)
__global__ void k_pack(const float* __restrict__ W2, const float* __restrict__ W3,
                       unsigned short* __restrict__ W2H, unsigned short* __restrict__ W2L,
                       unsigned short* __restrict__ W3H, unsigned short* __restrict__ W3L) {
  int tid = blockIdx.x * 256 + threadIdx.x;
  if (tid < 65536) {
    int j = tid & 7, lane = (tid >> 3) & 63, ks = (tid >> 9) & 15, ct = tid >> 13;
    int k = ks * 16 + ((lane >> 5) << 3) + j;
    int ch = ct * 32 + (lane & 31);
    float wv = W2[k * 256 + ch];
    unsigned short hi = f2bf(wv);
    unsigned short lo = f2bf(wv - bf2f(hi));
    W2H[tid] = hi; W2L[tid] = lo;
  } else if (tid < 65536 + 16384) {
    int t3 = tid - 65536;
    int j = t3 & 7, lane = (t3 >> 3) & 63, ks = (t3 >> 9) & 15, ct = t3 >> 13;
    int k = ks * 16 + ((lane >> 5) << 3) + j;
    int ch = ct * 32 + (lane & 31);
    float wv = W3[k * 64 + ch];
    unsigned short hi = f2bf(wv);
    unsigned short lo = f2bf(wv - bf2f(hi));
    W3H[t3] = hi; W3L[t3] = lo;
  }
}

// ---------- fused main kernel: 128 nodes per block ----------
__global__ void __launch_bounds__(256, 2)
k_main(const float* __restrict__ x, const int* __restrict__ bidx,
       const float* __restrict__ p0, const float* __restrict__ p1,
       const float* __restrict__ p2, const float* __restrict__ W1,
       const unsigned short* __restrict__ W2H, const unsigned short* __restrict__ W2L,
       const unsigned short* __restrict__ W3H, const unsigned short* __restrict__ W3L,
       const float* __restrict__ b2, const float* __restrict__ b3,
       const float* __restrict__ W4, const float* __restrict__ b4,
       float* __restrict__ out, int N) {
  __shared__ unsigned short zbuf[128 * 256];  // 64 KB: z1/z2 [128][256], z3 [128][64]

  const int t = threadIdx.x;
  const int r = t >> 1, halfsel = t & 1;
  const int n = blockIdx.x * 128 + r;
  const bool valid = n < N;
  const float xv = valid ? x[n] : 0.0f;
  const int g = valid ? bidx[n] : 0;
  const float xm = xv - 0.5f;

  // ---- L1: z1[r][c] = GELU_taylor(t0 + w1[c]*(x-0.5)) as bf16 into LDS ----
  {
    const float* P0 = p0 + g * 256;
    const float* P1 = p1 + g * 256;
    const float* P2 = p2 + g * 256;
    const int cbase = halfsel * 128;
#pragma unroll 2
    for (int c0 = 0; c0 < 128; c0 += 8) {
      int c = cbase + c0;
      f32x4 a0 = *(const f32x4*)(P0 + c), a1 = *(const f32x4*)(P0 + c + 4);
      f32x4 q0 = *(const f32x4*)(P1 + c), q1 = *(const f32x4*)(P1 + c + 4);
      f32x4 s0 = *(const f32x4*)(P2 + c), s1 = *(const f32x4*)(P2 + c + 4);
      f32x4 w0 = *(const f32x4*)(W1 + c), w1v = *(const f32x4*)(W1 + c + 4);
      unsigned int pk[4];
      unsigned short rr[8];
#pragma unroll
      for (int i = 0; i < 4; i++) {
        float d = w0[i] * xm;
        rr[i] = f2bf(fmaf(d, fmaf(d, s0[i], q0[i]), a0[i]));
        float d2 = w1v[i] * xm;
        rr[4 + i] = f2bf(fmaf(d2, fmaf(d2, s1[i], q1[i]), a1[i]));
      }
      pk[0] = rr[0] | ((unsigned)rr[1] << 16);
      pk[1] = rr[2] | ((unsigned)rr[3] << 16);
      pk[2] = rr[4] | ((unsigned)rr[5] << 16);
      pk[3] = rr[6] | ((unsigned)rr[7] << 16);
      int byte = r * 512 + ((c * 2) ^ ((r & 7) << 4));
      *(uint4*)&zbuf[byte >> 1] = make_uint4(pk[0], pk[1], pk[2], pk[3]);
    }
  }
  __syncthreads();

  const int w = t >> 6, l = t & 63;
  const int l31 = l & 31, lg = l >> 5, l7 = l & 7;

  // ---- L2: C[ch 256][node 128] = (W2^T hi+lo) x z1^T ; wave w -> chtiles {2w,2w+1} ----
  f32x16 acc[2][4] = {};
  {
    const short8* w2h = (const short8*)W2H;
    const short8* w2l = (const short8*)W2L;
    const int fi0 = (2 * w + 0) * 16 * 64 + l;
    const int fi1 = (2 * w + 1) * 16 * 64 + l;
#pragma unroll 2
    for (int ks = 0; ks < 16; ks++) {
      short8 a00 = w2h[fi0 + ks * 64];
      short8 a01 = w2l[fi0 + ks * 64];
      short8 a10 = w2h[fi1 + ks * 64];
      short8 a11 = w2l[fi1 + ks * 64];
      int colx = (ks * 32 + lg * 16) ^ (l7 << 4);
      short8 bfr[4];
#pragma unroll
      for (int nt = 0; nt < 4; nt++) {
        int node = nt * 32 + l31;
        bfr[nt] = *(const short8*)&zbuf[(node * 512 + colx) >> 1];
      }
#pragma unroll
      for (int nt = 0; nt < 4; nt++) {
        acc[0][nt] = __builtin_amdgcn_mfma_f32_32x32x16_bf16(a00, bfr[nt], acc[0][nt], 0, 0, 0);
        acc[0][nt] = __builtin_amdgcn_mfma_f32_32x32x16_bf16(a01, bfr[nt], acc[0][nt], 0, 0, 0);
        acc[1][nt] = __builtin_amdgcn_mfma_f32_32x32x16_bf16(a10, bfr[nt], acc[1][nt], 0, 0, 0);
        acc[1][nt] = __builtin_amdgcn_mfma_f32_32x32x16_bf16(a11, bfr[nt], acc[1][nt], 0, 0, 0);
      }
    }
  }
  __syncthreads();  // all waves done reading z1

  // ---- L2 epilogue: z2 = gelu(acc + b2) -> bf16 LDS (same layout as z1) ----
#pragma unroll
  for (int ct = 0; ct < 2; ct++) {
    int cb = (2 * w + ct) * 32;
#pragma unroll
    for (int q = 0; q < 4; q++) {
      int ch = cb + 8 * q + 4 * lg;
      f32x4 bias = *(const f32x4*)(b2 + ch);
#pragma unroll
      for (int nt = 0; nt < 4; nt++) {
        int node = nt * 32 + l31;
        unsigned short rr[4];
#pragma unroll
        for (int i = 0; i < 4; i++) {
          float v = acc[ct][nt][4 * q + i] + bias[i];
          rr[i] = f2bf(gelu_erf(v));
        }
        int byte = node * 512 + ((ch * 2) ^ (l7 << 4));
        *(uint2*)&zbuf[byte >> 1] =
            make_uint2(rr[0] | ((unsigned)rr[1] << 16), rr[2] | ((unsigned)rr[3] << 16));
      }
    }
  }
  __syncthreads();

  // ---- L3: C[ch 64][node 128]; wave: chtile = w&1, nodes = (w>>1)*64.. ----
  const int ct3 = w & 1;
  const int nb3 = w >> 1;
  f32x16 acc3[2] = {};
  {
    const short8* w3h = (const short8*)W3H;
    const short8* w3l = (const short8*)W3L;
    const int fi = ct3 * 16 * 64 + l;
#pragma unroll 2
    for (int ks = 0; ks < 16; ks++) {
      short8 ah = w3h[fi + ks * 64];
      short8 al = w3l[fi + ks * 64];
      int colx = (ks * 32 + lg * 16) ^ (l7 << 4);
#pragma unroll
      for (int nt = 0; nt < 2; nt++) {
        int node = nb3 * 64 + nt * 32 + l31;
        short8 bfr = *(const short8*)&zbuf[(node * 512 + colx) >> 1];
        acc3[nt] = __builtin_amdgcn_mfma_f32_32x32x16_bf16(ah, bfr, acc3[nt], 0, 0, 0);
        acc3[nt] = __builtin_amdgcn_mfma_f32_32x32x16_bf16(al, bfr, acc3[nt], 0, 0, 0);
      }
    }
  }
  __syncthreads();  // all waves done reading z2

  // ---- L3 epilogue: z3 = gelu(acc3 + b3) -> bf16 LDS [128][64], stride 128B ----
#pragma unroll
  for (int q = 0; q < 4; q++) {
    int ch = ct3 * 32 + 8 * q + 4 * lg;
    f32x4 bias = *(const f32x4*)(b3 + ch);
#pragma unroll
    for (int nt = 0; nt < 2; nt++) {
      int node = nb3 * 64 + nt * 32 + l31;
      unsigned short rr[4];
#pragma unroll
      for (int i = 0; i < 4; i++) {
        float v = acc3[nt][4 * q + i] + bias[i];
        rr[i] = f2bf(gelu_erf(v));
      }
      int byte = node * 128 + ((ch * 2) ^ ((node & 7) << 4));
      *(uint2*)&zbuf[byte >> 1] =
          make_uint2(rr[0] | ((unsigned)rr[1] << 16), rr[2] | ((unsigned)rr[3] << 16));
    }
  }
  __syncthreads();

  // ---- L4 + pool: energy = z3 . W4 + b4 ; atomicAdd per node ----
  {
    float e = 0.f;
    const int hb = halfsel * 32;
#pragma unroll
    for (int cc = 0; cc < 32; cc += 8) {
      int ch = hb + cc;
      int byte = r * 128 + ((ch * 2) ^ ((r & 7) << 4));
      short8 v = *(const short8*)&zbuf[byte >> 1];
      f32x4 wa = *(const f32x4*)(W4 + ch);
      f32x4 wb = *(const f32x4*)(W4 + ch + 4);
#pragma unroll
      for (int i = 0; i < 4; i++) {
        e = fmaf(bf2f((unsigned short)v[i]), wa[i], e);
        e = fmaf(bf2f((unsigned short)v[4 + i]), wb[i], e);
      }
    }
    e += __shfl_xor(e, 1, 64);
    if (halfsel == 0 && valid) atomicAdd(out + g, e + b4[0]);
  }
}

extern "C" void kernel_launch(void* const* d_in, const int* in_sizes, int n_in,
                              void* d_out, int out_size, void* d_ws, size_t ws_size,
                              hipStream_t stream) {
  const float* x  = (const float*)d_in[0];
  const float* h  = (const float*)d_in[1];
  const int* bidx = (const int*)d_in[2];
  const float* W1 = (const float*)d_in[3];
  const float* b1 = (const float*)d_in[4];
  const float* W2 = (const float*)d_in[5];
  const float* b2 = (const float*)d_in[6];
  const float* W3 = (const float*)d_in[7];
  const float* b3 = (const float*)d_in[8];
  const float* W4 = (const float*)d_in[9];
  const float* b4 = (const float*)d_in[10];
  float* out = (float*)d_out;
  const int N = in_sizes[0];

  char* ws = (char*)d_ws;
  float* p0 = (float*)(ws);
  float* p1 = (float*)(ws + (1 << 20));
  float* p2 = (float*)(ws + (2 << 20));
  unsigned short* W2H = (unsigned short*)(ws + (3 << 20));
  unsigned short* W2L = (unsigned short*)(ws + (3 << 20) + 131072);
  unsigned short* W3H = (unsigned short*)(ws + (3 << 20) + 262144);
  unsigned short* W3L = (unsigned short*)(ws + (3 << 20) + 262144 + 32768);

  hipMemsetAsync(d_out, 0, (size_t)out_size * sizeof(float), stream);
  k_graph<<<1024, 256, 0, stream>>>(h, W1, b1, p0, p1, p2);
  k_pack<<<320, 256, 0, stream>>>(W2, W3, W2H, W2L, W3H, W3L);
  const int nb = (N + 127) / 128;
  k_main<<<nb, 256, 0, stream>>>(x, bidx, p0, p1, p2, W1, W2H, W2L, W3H, W3L,
                                 b2, b3, W4, b4, out, N);
}

// Round 2
// 831.359 us; speedup vs baseline: 1.9766x; 1.9766x over previous
//
#include <hip/hip_runtime.h>
#include <hip/hip_bf16.h>

typedef short short8 __attribute__((ext_vector_type(8)));
typedef float f32x16 __attribute__((ext_vector_type(16)));
typedef float f32x4 __attribute__((ext_vector_type(4)));

// ---------- bf16 helpers (RNE) ----------
__device__ __forceinline__ unsigned short f2bf(float f) {
  union { float f; unsigned int u; } v; v.f = f;
  unsigned int u = v.u;
  unsigned int r = u + 0x7FFFu + ((u >> 16) & 1u);
  return (unsigned short)(r >> 16);
}
__device__ __forceinline__ float bf2f(unsigned short s) {
  union { unsigned int u; float f; } v; v.u = ((unsigned int)s) << 16;
  return v.f;
}

// ---------- erf / GELU (A&S 7.1.26, |err| <= 1.5e-7) ----------
__device__ __forceinline__ float erfc_core(float u) {  // ~erfc(u), u>=0
  float e = __expf(-u * u);
  float d = fmaf(0.3275911f, u, 1.0f);
  float r = __builtin_amdgcn_rcpf(d);
  float p = fmaf(1.061405429f, r, -1.453152027f);
  p = fmaf(p, r, 1.421413741f);
  p = fmaf(p, r, -0.284496736f);
  p = fmaf(p, r, 0.254829592f);
  p = p * r;
  return p * e;
}
__device__ __forceinline__ float gelu_erf(float t) {
  float u = fabsf(t) * 0.7071067811865475f;
  float w = erfc_core(u);
  float h = 0.5f * fabsf(t);
  return fmaf(-h, w, fmaf(0.5f, t, h));  // 0.5t + h*(1-w)
}

// ---------- per-(graph,channel) GELU Taylor coeffs ----------
__global__ void k_graph(const float* __restrict__ h, const float* __restrict__ W1,
                        const float* __restrict__ b1,
                        float* __restrict__ p0, float* __restrict__ p1,
                        float* __restrict__ p2) {
  __shared__ float hs[128];
  int g = blockIdx.x, c = threadIdx.x;
  if (c < 128) hs[c] = h[g * 128 + c];
  __syncthreads();
  float acc = b1[c];
#pragma unroll 8
  for (int k = 0; k < 128; k++)
    acc = fmaf(hs[k], W1[(1 + k) * 256 + c], acc);
  float t0 = fmaf(0.5f, W1[c], acc);
  float u = fabsf(t0) * 0.7071067811865475f;
  float wq = erfc_core(u);
  float Phi = (t0 >= 0.f) ? fmaf(-0.5f, wq, 1.0f) : 0.5f * wq;
  float phi = 0.3989422804f * __expf(-0.5f * t0 * t0);
  int o = g * 256 + c;
  p0[o] = t0 * Phi;
  p1[o] = fmaf(t0, phi, Phi);
  p2[o] = phi * fmaf(-0.5f * t0, t0, 1.0f);
}

// ---------- pack W2/W3 to per-lane MFMA A-fragments, bf16 hi+lo ----------
// frag idx: ((chtile*16 + ks)*64 + lane)*8 + j ; k = ks*16+(lane>>5)*8+j ; ch = chtile*32+(lane&31)
__global__ void k_pack(const float* __restrict__ W2, const float* __restrict__ W3,
                       unsigned short* __restrict__ W2H, unsigned short* __restrict__ W2L,
                       unsigned short* __restrict__ W3H, unsigned short* __restrict__ W3L) {
  int tid = blockIdx.x * 256 + threadIdx.x;
  if (tid < 65536) {
    int j = tid & 7, lane = (tid >> 3) & 63, ks = (tid >> 9) & 15, ct = tid >> 13;
    int k = ks * 16 + ((lane >> 5) << 3) + j;
    int ch = ct * 32 + (lane & 31);
    float wv = W2[k * 256 + ch];
    unsigned short hi = f2bf(wv);
    W2H[tid] = hi; W2L[tid] = f2bf(wv - bf2f(hi));
  } else if (tid < 65536 + 16384) {
    int t3 = tid - 65536;
    int j = t3 & 7, lane = (t3 >> 3) & 63, ks = (t3 >> 9) & 15, ct = t3 >> 13;
    int k = ks * 16 + ((lane >> 5) << 3) + j;
    int ch = ct * 32 + (lane & 31);
    float wv = W3[k * 64 + ch];
    unsigned short hi = f2bf(wv);
    W3H[t3] = hi; W3L[t3] = f2bf(wv - bf2f(hi));
  }
}

// ---------- fused main kernel: 64 nodes / 256 threads / 32KB LDS ----------
__global__ void __launch_bounds__(256, 5)
k_main(const float* __restrict__ x, const int* __restrict__ bidx,
       const float* __restrict__ p0, const float* __restrict__ p1,
       const float* __restrict__ p2, const float* __restrict__ W1,
       const unsigned short* __restrict__ W2H, const unsigned short* __restrict__ W2L,
       const unsigned short* __restrict__ W3H, const unsigned short* __restrict__ W3L,
       const float* __restrict__ b2, const float* __restrict__ b3,
       const float* __restrict__ W4, const float* __restrict__ b4,
       float* __restrict__ out, int N) {
  __shared__ unsigned short zbuf[64 * 256];  // 32 KB, reused z1 -> z2

  const int t = threadIdx.x;

  // ---- L1: z1[r][c] = GELU_taylor(t0 + w1[c]*(x-0.5)) -> bf16 LDS ----
  {
    const int r = t >> 2, q4 = t & 3;           // node, channel-quarter
    const int n = blockIdx.x * 64 + r;
    const bool valid = n < N;
    const float xv = valid ? x[n] : 0.0f;
    const int g = valid ? bidx[n] : 0;
    const float xm = xv - 0.5f;
    const float* P0 = p0 + g * 256;
    const float* P1 = p1 + g * 256;
    const float* P2 = p2 + g * 256;
    const int cbase = q4 * 64;
#pragma unroll 2
    for (int c0 = 0; c0 < 64; c0 += 8) {
      int c = cbase + c0;
      f32x4 a0 = *(const f32x4*)(P0 + c), a1 = *(const f32x4*)(P0 + c + 4);
      f32x4 q0 = *(const f32x4*)(P1 + c), q1 = *(const f32x4*)(P1 + c + 4);
      f32x4 s0 = *(const f32x4*)(P2 + c), s1 = *(const f32x4*)(P2 + c + 4);
      f32x4 w0 = *(const f32x4*)(W1 + c), w1v = *(const f32x4*)(W1 + c + 4);
      unsigned short rr[8];
#pragma unroll
      for (int i = 0; i < 4; i++) {
        float d = w0[i] * xm;
        rr[i] = f2bf(fmaf(d, fmaf(d, s0[i], q0[i]), a0[i]));
        float d2 = w1v[i] * xm;
        rr[4 + i] = f2bf(fmaf(d2, fmaf(d2, s1[i], q1[i]), a1[i]));
      }
      int byte = r * 512 + ((c * 2) ^ ((r & 7) << 4));
      *(uint4*)&zbuf[byte >> 1] =
          make_uint4(rr[0] | ((unsigned)rr[1] << 16), rr[2] | ((unsigned)rr[3] << 16),
                     rr[4] | ((unsigned)rr[5] << 16), rr[6] | ((unsigned)rr[7] << 16));
    }
  }
  __syncthreads();

  const int w = t >> 6, l = t & 63;
  const int l31 = l & 31, lg = l >> 5, l7 = l & 7;

  // ---- L2: C[ch 256][node 64]; wave w -> chtiles {2w,2w+1}, nt in {0,1} ----
  f32x16 acc[2][2] = {};
  {
    const short8* w2h = (const short8*)W2H;
    const short8* w2l = (const short8*)W2L;
    const int fi0 = (2 * w + 0) * 1024 + l;
    const int fi1 = (2 * w + 1) * 1024 + l;
#pragma unroll 2
    for (int ks = 0; ks < 16; ks++) {
      short8 a00 = w2h[fi0 + ks * 64];
      short8 a01 = w2l[fi0 + ks * 64];
      short8 a10 = w2h[fi1 + ks * 64];
      short8 a11 = w2l[fi1 + ks * 64];
      int colx = (ks * 32 + lg * 16) ^ (l7 << 4);
      short8 bfr[2];
#pragma unroll
      for (int nt = 0; nt < 2; nt++)
        bfr[nt] = *(const short8*)&zbuf[((nt * 32 + l31) * 512 + colx) >> 1];
#pragma unroll
      for (int nt = 0; nt < 2; nt++) {
        acc[0][nt] = __builtin_amdgcn_mfma_f32_32x32x16_bf16(a00, bfr[nt], acc[0][nt], 0, 0, 0);
        acc[0][nt] = __builtin_amdgcn_mfma_f32_32x32x16_bf16(a01, bfr[nt], acc[0][nt], 0, 0, 0);
        acc[1][nt] = __builtin_amdgcn_mfma_f32_32x32x16_bf16(a10, bfr[nt], acc[1][nt], 0, 0, 0);
        acc[1][nt] = __builtin_amdgcn_mfma_f32_32x32x16_bf16(a11, bfr[nt], acc[1][nt], 0, 0, 0);
      }
    }
  }
  __syncthreads();  // all waves done reading z1

  // ---- L2 epilogue: z2 = gelu(acc + b2) -> bf16 LDS (same layout) ----
#pragma unroll
  for (int ct = 0; ct < 2; ct++) {
    int cb = (2 * w + ct) * 32;
#pragma unroll
    for (int q = 0; q < 4; q++) {
      int ch = cb + 8 * q + 4 * lg;
      f32x4 bias = *(const f32x4*)(b2 + ch);
#pragma unroll
      for (int nt = 0; nt < 2; nt++) {
        int node = nt * 32 + l31;
        unsigned short rr[4];
#pragma unroll
        for (int i = 0; i < 4; i++)
          rr[i] = f2bf(gelu_erf(acc[ct][nt][4 * q + i] + bias[i]));
        int byte = node * 512 + ((ch * 2) ^ (l7 << 4));
        *(uint2*)&zbuf[byte >> 1] =
            make_uint2(rr[0] | ((unsigned)rr[1] << 16), rr[2] | ((unsigned)rr[3] << 16));
      }
    }
  }
  __syncthreads();

  // ---- L3: chtile ct3 = w&1 (64 ch), node half nb3 = w>>1 ----
  const int ct3 = w & 1;
  const int nb3 = w >> 1;
  f32x16 acc3 = {};
  {
    const short8* w3h = (const short8*)W3H;
    const short8* w3l = (const short8*)W3L;
    const int fi = ct3 * 1024 + l;
    const int node = nb3 * 32 + l31;
#pragma unroll 2
    for (int ks = 0; ks < 16; ks++) {
      short8 ah = w3h[fi + ks * 64];
      short8 al = w3l[fi + ks * 64];
      int colx = (ks * 32 + lg * 16) ^ (l7 << 4);
      short8 bfr = *(const short8*)&zbuf[(node * 512 + colx) >> 1];
      acc3 = __builtin_amdgcn_mfma_f32_32x32x16_bf16(ah, bfr, acc3, 0, 0, 0);
      acc3 = __builtin_amdgcn_mfma_f32_32x32x16_bf16(al, bfr, acc3, 0, 0, 0);
    }
  }

  // ---- L4 fused in registers: e = sum_ch gelu(acc3+b3)*W4 ----
  {
    float e = 0.f;
#pragma unroll
    for (int q = 0; q < 4; q++) {
      int ch = ct3 * 32 + 8 * q + 4 * lg;
      f32x4 b3v = *(const f32x4*)(b3 + ch);
      f32x4 w4v = *(const f32x4*)(W4 + ch);
#pragma unroll
      for (int i = 0; i < 4; i++)
        e = fmaf(gelu_erf(acc3[4 * q + i] + b3v[i]), w4v[i], e);
    }
    e += __shfl_xor(e, 32, 64);  // fold lg halves: full 32-ch chtile per lane

    int nl = blockIdx.x * 64 + nb3 * 32 + l31;
    bool nv = nl < N;
    int gl = nv ? bidx[nl] : 0;
    if (ct3 == 0) e += b4[0];  // bias added once per node (ct3==0 wave)
    if (!nv) e = 0.f;

    // segmented inclusive-right scan over sorted gl (lanes 0..31 meaningful)
#pragma unroll
    for (int d = 1; d < 32; d <<= 1) {
      float eo = __shfl_down(e, d, 64);
      int go = __shfl_down(gl, d, 64);
      if (l31 + d < 32 && go == gl) e += eo;
    }
    int gp = __shfl_up(gl, 1, 64);
    bool head = (l31 == 0) || (gp != gl);
    if (lg == 0 && head && nv) atomicAdd(out + gl, e);
  }
}

extern "C" void kernel_launch(void* const* d_in, const int* in_sizes, int n_in,
                              void* d_out, int out_size, void* d_ws, size_t ws_size,
                              hipStream_t stream) {
  const float* x  = (const float*)d_in[0];
  const float* h  = (const float*)d_in[1];
  const int* bidx = (const int*)d_in[2];
  const float* W1 = (const float*)d_in[3];
  const float* b1 = (const float*)d_in[4];
  const float* W2 = (const float*)d_in[5];
  const float* b2 = (const float*)d_in[6];
  const float* W3 = (const float*)d_in[7];
  const float* b3 = (const float*)d_in[8];
  const float* W4 = (const float*)d_in[9];
  const float* b4 = (const float*)d_in[10];
  float* out = (float*)d_out;
  const int N = in_sizes[0];

  char* ws = (char*)d_ws;
  float* p0 = (float*)(ws);
  float* p1 = (float*)(ws + (1 << 20));
  float* p2 = (float*)(ws + (2 << 20));
  unsigned short* W2H = (unsigned short*)(ws + (3 << 20));
  unsigned short* W2L = (unsigned short*)(ws + (3 << 20) + 131072);
  unsigned short* W3H = (unsigned short*)(ws + (3 << 20) + 262144);
  unsigned short* W3L = (unsigned short*)(ws + (3 << 20) + 262144 + 32768);

  hipMemsetAsync(d_out, 0, (size_t)out_size * sizeof(float), stream);
  k_graph<<<1024, 256, 0, stream>>>(h, W1, b1, p0, p1, p2);
  k_pack<<<320, 256, 0, stream>>>(W2, W3, W2H, W2L, W3H, W3L);
  const int nb = (N + 63) / 64;
  k_main<<<nb, 256, 0, stream>>>(x, bidx, p0, p1, p2, W1, W2H, W2L, W3H, W3L,
                                 b2, b3, W4, b4, out, N);
}

// Round 3
// 507.518 us; speedup vs baseline: 3.2379x; 1.6381x over previous
//
#include <hip/hip_runtime.h>
#include <hip/hip_bf16.h>

typedef short short8 __attribute__((ext_vector_type(8)));
typedef float f32x16 __attribute__((ext_vector_type(16)));
typedef float f32x4 __attribute__((ext_vector_type(4)));

// ---------- bf16 helpers (RNE) ----------
__device__ __forceinline__ unsigned short f2bf(float f) {
  union { float f; unsigned int u; } v; v.f = f;
  unsigned int u = v.u;
  unsigned int r = u + 0x7FFFu + ((u >> 16) & 1u);
  return (unsigned short)(r >> 16);
}
__device__ __forceinline__ float bf2f(unsigned short s) {
  union { unsigned int u; float f; } v; v.u = ((unsigned int)s) << 16;
  return v.f;
}

// ---------- erf / GELU (A&S 7.1.26, |err| <= 1.5e-7) ----------
__device__ __forceinline__ float erfc_core(float u) {  // ~erfc(u), u>=0
  float e = __expf(-u * u);
  float d = fmaf(0.3275911f, u, 1.0f);
  float r = __builtin_amdgcn_rcpf(d);
  float p = fmaf(1.061405429f, r, -1.453152027f);
  p = fmaf(p, r, 1.421413741f);
  p = fmaf(p, r, -0.284496736f);
  p = fmaf(p, r, 0.254829592f);
  p = p * r;
  return p * e;
}
__device__ __forceinline__ float gelu_erf(float t) {
  float u = fabsf(t) * 0.7071067811865475f;
  float w = erfc_core(u);
  float h = 0.5f * fabsf(t);
  return fmaf(-h, w, fmaf(0.5f, t, h));  // 0.5t + h*(1-w)
}

// ---------- per-(graph,channel) GELU Taylor coeffs ----------
__global__ void k_graph(const float* __restrict__ h, const float* __restrict__ W1,
                        const float* __restrict__ b1,
                        float* __restrict__ p0, float* __restrict__ p1,
                        float* __restrict__ p2) {
  __shared__ float hs[128];
  int g = blockIdx.x, c = threadIdx.x;
  if (c < 128) hs[c] = h[g * 128 + c];
  __syncthreads();
  float acc = b1[c];
#pragma unroll 8
  for (int k = 0; k < 128; k++)
    acc = fmaf(hs[k], W1[(1 + k) * 256 + c], acc);
  float t0 = fmaf(0.5f, W1[c], acc);
  float u = fabsf(t0) * 0.7071067811865475f;
  float wq = erfc_core(u);
  float Phi = (t0 >= 0.f) ? fmaf(-0.5f, wq, 1.0f) : 0.5f * wq;
  float phi = 0.3989422804f * __expf(-0.5f * t0 * t0);
  int o = g * 256 + c;
  p0[o] = t0 * Phi;
  p1[o] = fmaf(t0, phi, Phi);
  p2[o] = phi * fmaf(-0.5f * t0, t0, 1.0f);
}

// ---------- pack W2/W3 to per-lane MFMA A-fragments, bf16 hi+lo ----------
// frag idx: ((chtile*16 + ks)*64 + lane)*8 + j ; k = ks*16+(lane>>5)*8+j ; ch = chtile*32+(lane&31)
__global__ void k_pack(const float* __restrict__ W2, const float* __restrict__ W3,
                       unsigned short* __restrict__ W2H, unsigned short* __restrict__ W2L,
                       unsigned short* __restrict__ W3H, unsigned short* __restrict__ W3L) {
  int tid = blockIdx.x * 256 + threadIdx.x;
  if (tid < 65536) {
    int j = tid & 7, lane = (tid >> 3) & 63, ks = (tid >> 9) & 15, ct = tid >> 13;
    int k = ks * 16 + ((lane >> 5) << 3) + j;
    int ch = ct * 32 + (lane & 31);
    float wv = W2[k * 256 + ch];
    unsigned short hi = f2bf(wv);
    W2H[tid] = hi; W2L[tid] = f2bf(wv - bf2f(hi));
  } else if (tid < 65536 + 16384) {
    int t3 = tid - 65536;
    int j = t3 & 7, lane = (t3 >> 3) & 63, ks = (t3 >> 9) & 15, ct = t3 >> 13;
    int k = ks * 16 + ((lane >> 5) << 3) + j;
    int ch = ct * 32 + (lane & 31);
    float wv = W3[k * 64 + ch];
    unsigned short hi = f2bf(wv);
    W3H[t3] = hi; W3L[t3] = f2bf(wv - bf2f(hi));
  }
}

// ---------- fused main: 64 nodes / 512 threads (8 waves) / 32KB LDS ----------
__global__ void __launch_bounds__(512, 6)
k_main(const float* __restrict__ x, const int* __restrict__ bidx,
       const float* __restrict__ p0, const float* __restrict__ p1,
       const float* __restrict__ p2, const float* __restrict__ W1,
       const unsigned short* __restrict__ W2H, const unsigned short* __restrict__ W2L,
       const unsigned short* __restrict__ W3H, const unsigned short* __restrict__ W3L,
       const float* __restrict__ b2, const float* __restrict__ b3,
       const float* __restrict__ W4, const float* __restrict__ b4,
       float* __restrict__ out, int N) {
  __shared__ unsigned short zbuf[64 * 256];  // 32 KB, reused z1 -> z2

  const int t = threadIdx.x;
  const int w = t >> 6, l = t & 63;
  const int l31 = l & 31, lg = l >> 5, l7 = l & 7;

  // ---- L1: z1[r][c] = GELU_taylor(t0 + w1[c]*(x-0.5)) -> bf16 LDS ----
  {
    const int r = w * 8 + (l >> 3);  // node 0..63
    const int ck = l & 7;            // 8-ch chunk within 64-ch stripe
    const int n = blockIdx.x * 64 + r;
    const bool valid = n < N;
    const float xv = valid ? x[n] : 0.0f;
    const int g = valid ? bidx[n] : 0;
    const float xm = xv - 0.5f;
    const float* P0 = p0 + g * 256;
    const float* P1 = p1 + g * 256;
    const float* P2 = p2 + g * 256;
#pragma unroll
    for (int it = 0; it < 4; it++) {
      int c = ck * 8 + it * 64;
      f32x4 a0 = *(const f32x4*)(P0 + c), a1 = *(const f32x4*)(P0 + c + 4);
      f32x4 q0 = *(const f32x4*)(P1 + c), q1 = *(const f32x4*)(P1 + c + 4);
      f32x4 s0 = *(const f32x4*)(P2 + c), s1 = *(const f32x4*)(P2 + c + 4);
      f32x4 w0 = *(const f32x4*)(W1 + c), w1v = *(const f32x4*)(W1 + c + 4);
      unsigned short rr[8];
#pragma unroll
      for (int i = 0; i < 4; i++) {
        float d = w0[i] * xm;
        rr[i] = f2bf(fmaf(d, fmaf(d, s0[i], q0[i]), a0[i]));
        float d2 = w1v[i] * xm;
        rr[4 + i] = f2bf(fmaf(d2, fmaf(d2, s1[i], q1[i]), a1[i]));
      }
      int byte = r * 512 + ((c * 2) ^ ((r & 7) << 4));
      *(uint4*)&zbuf[byte >> 1] =
          make_uint4(rr[0] | ((unsigned)rr[1] << 16), rr[2] | ((unsigned)rr[3] << 16),
                     rr[4] | ((unsigned)rr[5] << 16), rr[6] | ((unsigned)rr[7] << 16));
    }
  }
  __syncthreads();

  // ---- L2: C[ch 256][node 64]; wave w -> chtile w (32 ch), nt in {0,1} ----
  f32x16 acc[2] = {};
  {
    const short8* w2h = (const short8*)W2H;
    const short8* w2l = (const short8*)W2L;
    const int fi = w * 1024 + l;
#pragma unroll 2
    for (int ks = 0; ks < 16; ks++) {
      short8 ah = w2h[fi + ks * 64];
      short8 al = w2l[fi + ks * 64];
      int colx = (ks * 32 + lg * 16) ^ (l7 << 4);
      short8 b0 = *(const short8*)&zbuf[((l31) * 512 + colx) >> 1];
      short8 b1v = *(const short8*)&zbuf[((32 + l31) * 512 + colx) >> 1];
      acc[0] = __builtin_amdgcn_mfma_f32_32x32x16_bf16(ah, b0, acc[0], 0, 0, 0);
      acc[0] = __builtin_amdgcn_mfma_f32_32x32x16_bf16(al, b0, acc[0], 0, 0, 0);
      acc[1] = __builtin_amdgcn_mfma_f32_32x32x16_bf16(ah, b1v, acc[1], 0, 0, 0);
      acc[1] = __builtin_amdgcn_mfma_f32_32x32x16_bf16(al, b1v, acc[1], 0, 0, 0);
    }
  }
  __syncthreads();  // all waves done reading z1

  // ---- L2 epilogue: z2 = gelu(acc + b2) -> bf16 LDS (same layout) ----
  {
    const int cb = w * 32;
#pragma unroll
    for (int q = 0; q < 4; q++) {
      int ch = cb + 8 * q + 4 * lg;
      f32x4 bias = *(const f32x4*)(b2 + ch);
#pragma unroll
      for (int nt = 0; nt < 2; nt++) {
        int node = nt * 32 + l31;
        unsigned short rr[4];
#pragma unroll
        for (int i = 0; i < 4; i++)
          rr[i] = f2bf(gelu_erf(acc[nt][4 * q + i] + bias[i]));
        int byte = node * 512 + ((ch * 2) ^ (l7 << 4));
        *(uint2*)&zbuf[byte >> 1] =
            make_uint2(rr[0] | ((unsigned)rr[1] << 16), rr[2] | ((unsigned)rr[3] << 16));
      }
    }
  }
  __syncthreads();

  // ---- L3 + L4 + pool: waves 0..3 only ----
  if (w < 4) {
    const int ct3 = w & 1;
    const int nb3 = w >> 1;
    f32x16 acc3 = {};
    {
      const short8* w3h = (const short8*)W3H;
      const short8* w3l = (const short8*)W3L;
      const int fi = ct3 * 1024 + l;
      const int node = nb3 * 32 + l31;
#pragma unroll 2
      for (int ks = 0; ks < 16; ks++) {
        short8 ah = w3h[fi + ks * 64];
        short8 al = w3l[fi + ks * 64];
        int colx = (ks * 32 + lg * 16) ^ (l7 << 4);
        short8 bfr = *(const short8*)&zbuf[(node * 512 + colx) >> 1];
        acc3 = __builtin_amdgcn_mfma_f32_32x32x16_bf16(ah, bfr, acc3, 0, 0, 0);
        acc3 = __builtin_amdgcn_mfma_f32_32x32x16_bf16(al, bfr, acc3, 0, 0, 0);
      }
    }
    // L4 fused in registers: e = sum_ch gelu(acc3+b3)*W4
    float e = 0.f;
#pragma unroll
    for (int q = 0; q < 4; q++) {
      int ch = ct3 * 32 + 8 * q + 4 * lg;
      f32x4 b3v = *(const f32x4*)(b3 + ch);
      f32x4 w4v = *(const f32x4*)(W4 + ch);
#pragma unroll
      for (int i = 0; i < 4; i++)
        e = fmaf(gelu_erf(acc3[4 * q + i] + b3v[i]), w4v[i], e);
    }
    e += __shfl_xor(e, 32, 64);  // fold lg halves: full 32-ch chtile per lane

    int nl = blockIdx.x * 64 + nb3 * 32 + l31;
    bool nv = nl < N;
    int gl = nv ? bidx[nl] : -1;
    if (ct3 == 0) e += b4[0];  // bias added once per node
    if (!nv) e = 0.f;

    // segmented inclusive-right scan over sorted gl (32-lane groups)
#pragma unroll
    for (int d = 1; d < 32; d <<= 1) {
      float eo = __shfl_down(e, d, 64);
      int go = __shfl_down(gl, d, 64);
      if (l31 + d < 32 && go == gl) e += eo;
    }
    int gp = __shfl_up(gl, 1, 64);
    bool head = (l31 == 0) || (gp != gl);
    if (lg == 0 && head && nv) atomicAdd(out + gl, e);
  }
}

extern "C" void kernel_launch(void* const* d_in, const int* in_sizes, int n_in,
                              void* d_out, int out_size, void* d_ws, size_t ws_size,
                              hipStream_t stream) {
  const float* x  = (const float*)d_in[0];
  const float* h  = (const float*)d_in[1];
  const int* bidx = (const int*)d_in[2];
  const float* W1 = (const float*)d_in[3];
  const float* b1 = (const float*)d_in[4];
  const float* W2 = (const float*)d_in[5];
  const float* b2 = (const float*)d_in[6];
  const float* W3 = (const float*)d_in[7];
  const float* b3 = (const float*)d_in[8];
  const float* W4 = (const float*)d_in[9];
  const float* b4 = (const float*)d_in[10];
  float* out = (float*)d_out;
  const int N = in_sizes[0];

  char* ws = (char*)d_ws;
  float* p0 = (float*)(ws);
  float* p1 = (float*)(ws + (1 << 20));
  float* p2 = (float*)(ws + (2 << 20));
  unsigned short* W2H = (unsigned short*)(ws + (3 << 20));
  unsigned short* W2L = (unsigned short*)(ws + (3 << 20) + 131072);
  unsigned short* W3H = (unsigned short*)(ws + (3 << 20) + 262144);
  unsigned short* W3L = (unsigned short*)(ws + (3 << 20) + 262144 + 32768);

  hipMemsetAsync(d_out, 0, (size_t)out_size * sizeof(float), stream);
  k_graph<<<1024, 256, 0, stream>>>(h, W1, b1, p0, p1, p2);
  k_pack<<<320, 256, 0, stream>>>(W2, W3, W2H, W2L, W3H, W3L);
  const int nb = (N + 63) / 64;
  k_main<<<nb, 512, 0, stream>>>(x, bidx, p0, p1, p2, W1, W2H, W2L, W3H, W3L,
                                 b2, b3, W4, b4, out, N);
}

// Round 4
// 480.900 us; speedup vs baseline: 3.4171x; 1.0553x over previous
//
#include <hip/hip_runtime.h>
#include <hip/hip_bf16.h>

typedef short short8 __attribute__((ext_vector_type(8)));
typedef float f32x16 __attribute__((ext_vector_type(16)));
typedef float f32x4 __attribute__((ext_vector_type(4)));

// ---------- bf16 helpers ----------
__device__ __forceinline__ unsigned short f2bf(float f) {  // manual RNE (host-side packing kernels)
  union { float f; unsigned int u; } v; v.f = f;
  unsigned int u = v.u;
  unsigned int r = u + 0x7FFFu + ((u >> 16) & 1u);
  return (unsigned short)(r >> 16);
}
__device__ __forceinline__ float bf2f(unsigned short s) {
  union { unsigned int u; float f; } v; v.u = ((unsigned int)s) << 16;
  return v.f;
}
__device__ __forceinline__ unsigned packbf2(float a, float b) {  // let compiler emit cvt_pk
  union { __hip_bfloat162 h; unsigned u; } cv;
  cv.h = __hip_bfloat162{__float2bfloat16(a), __float2bfloat16(b)};
  return cv.u;
}

// ---------- erf / GELU (A&S 7.1.25 3-term, |err| <= 2.5e-5) ----------
__device__ __forceinline__ float erfc_core(float u) {  // ~erfc(u), u>=0
  float e = __expf(-u * u);
  float d = fmaf(0.47047f, u, 1.0f);
  float r = __builtin_amdgcn_rcpf(d);
  float p = fmaf(0.7478556f, r, -0.0958798f);
  p = fmaf(p, r, 0.3480242f);
  p = p * r;
  return p * e;
}
__device__ __forceinline__ float gelu_erf(float t) {
  float u = fabsf(t) * 0.7071067811865475f;
  float w = erfc_core(u);
  float h = 0.5f * fabsf(t);
  return fmaf(-h, w, fmaf(0.5f, t, h));  // 0.5t + h*(1-w)
}

// ---------- per-(graph,channel) Taylor coeffs with W1 folded in ----------
// t0 = b1 + h.W1[1:] + 0.5*w1c ; p0=gelu(t0), q1=w1c*gelu'(t0), q2=w1c^2*0.5*gelu''(t0)
__global__ void k_graph(const float* __restrict__ h, const float* __restrict__ W1,
                        const float* __restrict__ b1,
                        float* __restrict__ p0, float* __restrict__ q1,
                        float* __restrict__ q2) {
  __shared__ float hs[128];
  int g = blockIdx.x, c = threadIdx.x;
  if (c < 128) hs[c] = h[g * 128 + c];
  __syncthreads();
  float acc = b1[c];
#pragma unroll 8
  for (int k = 0; k < 128; k++)
    acc = fmaf(hs[k], W1[(1 + k) * 256 + c], acc);
  float w1c = W1[c];
  float t0 = fmaf(0.5f, w1c, acc);
  float u = fabsf(t0) * 0.7071067811865475f;
  float wq = erfc_core(u);
  float Phi = (t0 >= 0.f) ? fmaf(-0.5f, wq, 1.0f) : 0.5f * wq;
  float phi = 0.3989422804f * __expf(-0.5f * t0 * t0);
  int o = g * 256 + c;
  p0[o] = t0 * Phi;
  q1[o] = w1c * fmaf(t0, phi, Phi);
  q2[o] = (w1c * w1c) * (phi * fmaf(-0.5f * t0, t0, 1.0f));
}

// ---------- pack W2/W3 to per-lane MFMA A-fragments, bf16 hi+lo ----------
__global__ void k_pack(const float* __restrict__ W2, const float* __restrict__ W3,
                       unsigned short* __restrict__ W2H, unsigned short* __restrict__ W2L,
                       unsigned short* __restrict__ W3H, unsigned short* __restrict__ W3L) {
  int tid = blockIdx.x * 256 + threadIdx.x;
  if (tid < 65536) {
    int j = tid & 7, lane = (tid >> 3) & 63, ks = (tid >> 9) & 15, ct = tid >> 13;
    int k = ks * 16 + ((lane >> 5) << 3) + j;
    int ch = ct * 32 + (lane & 31);
    float wv = W2[k * 256 + ch];
    unsigned short hi = f2bf(wv);
    W2H[tid] = hi; W2L[tid] = f2bf(wv - bf2f(hi));
  } else if (tid < 65536 + 16384) {
    int t3 = tid - 65536;
    int j = t3 & 7, lane = (t3 >> 3) & 63, ks = (t3 >> 9) & 15, ct = t3 >> 13;
    int k = ks * 16 + ((lane >> 5) << 3) + j;
    int ch = ct * 32 + (lane & 31);
    float wv = W3[k * 64 + ch];
    unsigned short hi = f2bf(wv);
    W3H[t3] = hi; W3L[t3] = f2bf(wv - bf2f(hi));
  }
}

// zbuf swizzle: byte = row*512 + (colbyte ^ ((row&7)<<4) ^ (((row>>3)&3)<<7))
// ---------- fused main: 64 nodes / 512 threads (8 waves) ----------
__global__ void __launch_bounds__(512, 8)
k_main(const float* __restrict__ x, const int* __restrict__ bidx,
       const float* __restrict__ p0, const float* __restrict__ q1,
       const float* __restrict__ q2,
       const unsigned short* __restrict__ W2H, const unsigned short* __restrict__ W2L,
       const unsigned short* __restrict__ W3H, const unsigned short* __restrict__ W3L,
       const float* __restrict__ b2, const float* __restrict__ b3,
       const float* __restrict__ W4, const float* __restrict__ b4,
       float* __restrict__ out, int N) {
  __shared__ unsigned short zbuf[64 * 256];  // 32 KB, z1 -> z2
  __shared__ float cf[3][512];               // 6 KB staged coeffs (2 graphs)

  const int t = threadIdx.x;
  const int w = t >> 6, l = t & 63;
  const int l31 = l & 31, lg = l >> 5, l7 = l & 7;
  const int base = blockIdx.x * 64;

  // stage Taylor coeffs for graphs gfirst, gfirst+1
  const int gfirst = bidx[min(base, N - 1)];
  {
    int s = t >> 8, c = t & 255;
    int gs = min(gfirst + s, 1023);
    cf[0][s * 256 + c] = p0[gs * 256 + c];
    cf[1][s * 256 + c] = q1[gs * 256 + c];
    cf[2][s * 256 + c] = q2[gs * 256 + c];
  }
  // node data: row = lane (coalesced)
  const int n = base + l;
  const bool valid = n < N;
  const float xv = valid ? x[n] : 0.0f;
  const int g = valid ? bidx[n] : gfirst;
  const float xm = xv - 0.5f;
  const int dg = g - gfirst;
  const int rswz = ((l & 7) << 4) ^ (((l >> 3) & 3) << 7);
  __syncthreads();

  // ---- L1: z1[l][c] = p0 + xm*(q1 + xm*q2), wave w owns channels [32w,32w+32) ----
  {
#pragma unroll
    for (int it = 0; it < 8; it++) {
      int c = w * 32 + it * 4;
      f32x4 a, q, s;
      if (dg <= 1) {
        a = *(const f32x4*)&cf[0][dg * 256 + c];
        q = *(const f32x4*)&cf[1][dg * 256 + c];
        s = *(const f32x4*)&cf[2][dg * 256 + c];
      } else {  // rare: block spans >2 graphs
        a = *(const f32x4*)(p0 + g * 256 + c);
        q = *(const f32x4*)(q1 + g * 256 + c);
        s = *(const f32x4*)(q2 + g * 256 + c);
      }
      float v0 = fmaf(xm, fmaf(xm, s[0], q[0]), a[0]);
      float v1 = fmaf(xm, fmaf(xm, s[1], q[1]), a[1]);
      float v2 = fmaf(xm, fmaf(xm, s[2], q[2]), a[2]);
      float v3 = fmaf(xm, fmaf(xm, s[3], q[3]), a[3]);
      int byte = l * 512 + ((c * 2) ^ rswz);
      *(uint2*)&zbuf[byte >> 1] = make_uint2(packbf2(v0, v1), packbf2(v2, v3));
    }
  }
  __syncthreads();

  // ---- L2: C[ch 256][node 64]; wave w -> chtile w; acc pre-init with b2 ----
  f32x16 acc[2];
  {
    const int cb = w * 32;
#pragma unroll
    for (int q = 0; q < 4; q++) {
      f32x4 bias = *(const f32x4*)(b2 + cb + 8 * q + 4 * lg);
#pragma unroll
      for (int i = 0; i < 4; i++) { acc[0][4 * q + i] = bias[i]; acc[1][4 * q + i] = bias[i]; }
    }
    const short8* w2h = (const short8*)W2H;
    const short8* w2l = (const short8*)W2L;
    const int fi = w * 1024 + l;
    const int bswz = (l7 << 4) ^ (((l31 >> 3) & 3) << 7);
#pragma unroll 2
    for (int ks = 0; ks < 16; ks++) {
      short8 ah = w2h[fi + ks * 64];
      short8 al = w2l[fi + ks * 64];
      int colx = (ks * 32 + lg * 16) ^ bswz;
      short8 b0 = *(const short8*)&zbuf[(l31 * 512 + colx) >> 1];
      short8 b1v = *(const short8*)&zbuf[((32 + l31) * 512 + colx) >> 1];
      acc[0] = __builtin_amdgcn_mfma_f32_32x32x16_bf16(ah, b0, acc[0], 0, 0, 0);
      acc[0] = __builtin_amdgcn_mfma_f32_32x32x16_bf16(al, b0, acc[0], 0, 0, 0);
      acc[1] = __builtin_amdgcn_mfma_f32_32x32x16_bf16(ah, b1v, acc[1], 0, 0, 0);
      acc[1] = __builtin_amdgcn_mfma_f32_32x32x16_bf16(al, b1v, acc[1], 0, 0, 0);
    }
  }
  __syncthreads();  // all waves done reading z1

  // ---- L2 epilogue: z2 = gelu(acc) -> bf16 LDS (same swizzled layout) ----
  {
    const int cb = w * 32;
#pragma unroll
    for (int q = 0; q < 4; q++) {
      int ch = cb + 8 * q + 4 * lg;
#pragma unroll
      for (int nt = 0; nt < 2; nt++) {
        int node = nt * 32 + l31;
        float g0 = gelu_erf(acc[nt][4 * q + 0]);
        float g1 = gelu_erf(acc[nt][4 * q + 1]);
        float g2 = gelu_erf(acc[nt][4 * q + 2]);
        float g3 = gelu_erf(acc[nt][4 * q + 3]);
        int byte = node * 512 + ((ch * 2) ^ ((node & 7) << 4) ^ (((node >> 3) & 3) << 7));
        *(uint2*)&zbuf[byte >> 1] = make_uint2(packbf2(g0, g1), packbf2(g2, g3));
      }
    }
  }
  __syncthreads();

  // ---- L3 + L4 + pool: waves 0..3 ----
  if (w < 4) {
    const int ct3 = w & 1;
    const int nb3 = w >> 1;
    f32x16 acc3;
#pragma unroll
    for (int q = 0; q < 4; q++) {
      f32x4 bias = *(const f32x4*)(b3 + ct3 * 32 + 8 * q + 4 * lg);
#pragma unroll
      for (int i = 0; i < 4; i++) acc3[4 * q + i] = bias[i];
    }
    {
      const short8* w3h = (const short8*)W3H;
      const short8* w3l = (const short8*)W3L;
      const int fi = ct3 * 1024 + l;
      const int node = nb3 * 32 + l31;
      const int bswz = ((node & 7) << 4) ^ (((node >> 3) & 3) << 7);
#pragma unroll 2
      for (int ks = 0; ks < 16; ks++) {
        short8 ah = w3h[fi + ks * 64];
        short8 al = w3l[fi + ks * 64];
        int colx = (ks * 32 + lg * 16) ^ bswz;
        short8 bfr = *(const short8*)&zbuf[(node * 512 + colx) >> 1];
        acc3 = __builtin_amdgcn_mfma_f32_32x32x16_bf16(ah, bfr, acc3, 0, 0, 0);
        acc3 = __builtin_amdgcn_mfma_f32_32x32x16_bf16(al, bfr, acc3, 0, 0, 0);
      }
    }
    // L4 fused: e = sum_ch gelu(acc3)*W4
    float e = 0.f;
#pragma unroll
    for (int q = 0; q < 4; q++) {
      f32x4 w4v = *(const f32x4*)(W4 + ct3 * 32 + 8 * q + 4 * lg);
#pragma unroll
      for (int i = 0; i < 4; i++)
        e = fmaf(gelu_erf(acc3[4 * q + i]), w4v[i], e);
    }
    e += __shfl_xor(e, 32, 64);  // fold lg halves

    int nl = base + nb3 * 32 + l31;
    bool nv = nl < N;
    int gl = nv ? bidx[nl] : -1;
    if (ct3 == 0) e += b4[0];  // once per node
    if (!nv) e = 0.f;

    // segmented scan over sorted gl within 32-lane groups
#pragma unroll
    for (int d = 1; d < 32; d <<= 1) {
      float eo = __shfl_down(e, d, 64);
      int go = __shfl_down(gl, d, 64);
      if (l31 + d < 32 && go == gl) e += eo;
    }
    int gp = __shfl_up(gl, 1, 64);
    bool head = (l31 == 0) || (gp != gl);
    if (lg == 0 && head && nv) atomicAdd(out + gl, e);
  }
}

extern "C" void kernel_launch(void* const* d_in, const int* in_sizes, int n_in,
                              void* d_out, int out_size, void* d_ws, size_t ws_size,
                              hipStream_t stream) {
  const float* x  = (const float*)d_in[0];
  const float* h  = (const float*)d_in[1];
  const int* bidx = (const int*)d_in[2];
  const float* W1 = (const float*)d_in[3];
  const float* b1 = (const float*)d_in[4];
  const float* W2 = (const float*)d_in[5];
  const float* b2 = (const float*)d_in[6];
  const float* W3 = (const float*)d_in[7];
  const float* b3 = (const float*)d_in[8];
  const float* W4 = (const float*)d_in[9];
  const float* b4 = (const float*)d_in[10];
  float* out = (float*)d_out;
  const int N = in_sizes[0];

  char* ws = (char*)d_ws;
  float* p0 = (float*)(ws);
  float* q1 = (float*)(ws + (1 << 20));
  float* q2 = (float*)(ws + (2 << 20));
  unsigned short* W2H = (unsigned short*)(ws + (3 << 20));
  unsigned short* W2L = (unsigned short*)(ws + (3 << 20) + 131072);
  unsigned short* W3H = (unsigned short*)(ws + (3 << 20) + 262144);
  unsigned short* W3L = (unsigned short*)(ws + (3 << 20) + 262144 + 32768);

  hipMemsetAsync(d_out, 0, (size_t)out_size * sizeof(float), stream);
  k_graph<<<1024, 256, 0, stream>>>(h, W1, b1, p0, q1, q2);
  k_pack<<<320, 256, 0, stream>>>(W2, W3, W2H, W2L, W3H, W3L);
  const int nb = (N + 63) / 64;
  k_main<<<nb, 512, 0, stream>>>(x, bidx, p0, q1, q2, W2H, W2L, W3H, W3L,
                                 b2, b3, W4, b4, out, N);
}